// Round 3
// baseline (3144.450 us; speedup 1.0000x reference)
//
#include <hip/hip_runtime.h>

// MultiHeadAttention: B=16, S=1024, D=256, H=16, DK=16.
// ALL float tensors are float32 (per the reference; round-0/1/2 forensics:
// the "(bf16" in the harness label is a hardcoded f-string, and misreading
// f32 as bf16 explains the NaNs exactly). mask is int32.
// Outputs concatenated in d_out (float32):
//   out0   [16,1024,256]
//   attn_w [16,16,1024,1024]
//
//   proj_kernel      : q/k/v projections -> f32 workspace [B,S,256]
//   transpose_kernel : k,v -> [B*H, DK, S] f32 (coalesced attn staging)
//   attn_kernel      : per (b,h,16-row q-tile): chunked keys (128/chunk) in LDS;
//                      FMA scores; NaN-proof exp (clamp + mask branch); E strip
//                      bf16 in LDS; shfl-xor reductions for z and ctx; coalesced
//                      float4 attn_w write.

#define NB 16
#define NS 1024
#define ND 256
#define NH 16
#define NDK 16

static __device__ __forceinline__ float bf2f(unsigned int u) {
    union { unsigned int i; float f; } v;
    v.i = u << 16;
    return v.f;
}
static __device__ __forceinline__ unsigned short f2bf(float f) {
    union { float f; unsigned int i; } v;
    v.f = f;
    const unsigned int u = v.i;
    return (unsigned short)((u + 0x7fffu + ((u >> 16) & 1u)) >> 16);  // RNE
}

// ---------------------------------------------------------------------------
// Projections: rows = B*S = 16384, K = 256, cols = 256. f32 in/out.
// Block 256 = 8 teams x 32 lanes; team: 4 rows, lane: 8 consecutive cols.
// grid = (16384/32, 3).
// ---------------------------------------------------------------------------
__global__ __launch_bounds__(256) void proj_kernel(
    const float* __restrict__ Q, const float* __restrict__ K,
    const float* __restrict__ V,
    const float* __restrict__ Wq, const float* __restrict__ bq,
    const float* __restrict__ Wk, const float* __restrict__ Wv,
    const float* __restrict__ bv,
    float* __restrict__ q_ws, float* __restrict__ k_ws, float* __restrict__ v_ws)
{
    const int mat = blockIdx.y;
    const float* X    = (mat == 0) ? Q  : ((mat == 1) ? K  : V);
    const float* W    = (mat == 0) ? Wq : ((mat == 1) ? Wk : Wv);
    const float* bias = (mat == 0) ? bq : ((mat == 2) ? bv : nullptr);
    float* dst = (mat == 0) ? q_ws : ((mat == 1) ? k_ws : v_ws);

    __shared__ float Xs[32][256];  // 32 staged input rows (32 KB)

    const int tid = threadIdx.x;
    const int rbase = blockIdx.x * 32;

    // stage 32 rows: 2048 float4 chunks, coalesced
    for (int c = tid; c < 2048; c += 256) {
        const int row = c >> 6, c4 = (c & 63) * 4;
        *reinterpret_cast<float4*>(&Xs[row][c4]) =
            *reinterpret_cast<const float4*>(X + (size_t)(rbase + row) * ND + c4);
    }
    __syncthreads();

    const int team = tid >> 5;  // rows team*4 .. team*4+3
    const int l    = tid & 31;  // cols l*8 .. l*8+7

    float acc[4][8];
#pragma unroll
    for (int r = 0; r < 4; ++r)
#pragma unroll
        for (int j = 0; j < 8; ++j)
            acc[r][j] = bias ? bias[l * 8 + j] : 0.f;

    for (int i4 = 0; i4 < 64; ++i4) {
        float4 xv[4];
#pragma unroll
        for (int r = 0; r < 4; ++r)
            xv[r] = *reinterpret_cast<const float4*>(&Xs[team * 4 + r][i4 * 4]);
#pragma unroll
        for (int s = 0; s < 4; ++s) {
            const int i = i4 * 4 + s;
            const float4 w1 = *reinterpret_cast<const float4*>(W + i * ND + l * 8);
            const float4 w2 = *reinterpret_cast<const float4*>(W + i * ND + l * 8 + 4);
            const float w[8] = {w1.x, w1.y, w1.z, w1.w, w2.x, w2.y, w2.z, w2.w};
            const float xs[4] = {((const float*)&xv[0])[s], ((const float*)&xv[1])[s],
                                 ((const float*)&xv[2])[s], ((const float*)&xv[3])[s]};
#pragma unroll
            for (int r = 0; r < 4; ++r)
#pragma unroll
                for (int j = 0; j < 8; ++j)
                    acc[r][j] += xs[r] * w[j];
        }
    }

#pragma unroll
    for (int r = 0; r < 4; ++r) {
        const int g = rbase + team * 4 + r;
        float4 o1 = {acc[r][0], acc[r][1], acc[r][2], acc[r][3]};
        float4 o2 = {acc[r][4], acc[r][5], acc[r][6], acc[r][7]};
        *reinterpret_cast<float4*>(dst + (size_t)g * ND + l * 8)     = o1;
        *reinterpret_cast<float4*>(dst + (size_t)g * ND + l * 8 + 4) = o2;
    }
}

// ---------------------------------------------------------------------------
// Transpose k/v head-slices: [B,S,256] f32 -> [B*H, DK, S] f32.
// grid = (256 bh * 8 s-chunks, 2 mats), block 256.
// ---------------------------------------------------------------------------
__global__ __launch_bounds__(256) void transpose_kernel(
    const float* __restrict__ k_ws, const float* __restrict__ v_ws,
    float* __restrict__ kT, float* __restrict__ vT)
{
    const int mat = blockIdx.y;
    const float* src = mat ? v_ws : k_ws;
    float* dstp = mat ? vT : kT;

    __shared__ float T[128][17];

    const int bh = blockIdx.x >> 3, sc = blockIdx.x & 7;
    const int b = bh >> 4, h = bh & 15, s0 = sc * 128;
    const int tid = threadIdx.x;

#pragma unroll
    for (int it = 0; it < 2; ++it) {
        const int r = it * 64 + (tid >> 2), c4 = (tid & 3) * 4;
        const float4 vv = *reinterpret_cast<const float4*>(
            src + (size_t)(b * NS + s0 + r) * ND + h * NDK + c4);
        T[r][c4 + 0] = vv.x; T[r][c4 + 1] = vv.y;
        T[r][c4 + 2] = vv.z; T[r][c4 + 3] = vv.w;
    }
    __syncthreads();

    const int d = tid >> 4, si = (tid & 15) * 8;
    float o[8];
#pragma unroll
    for (int i = 0; i < 8; ++i) o[i] = T[si + i][d];
    float4 oa = {o[0], o[1], o[2], o[3]};
    float4 ob = {o[4], o[5], o[6], o[7]};
    float* dp = dstp + (size_t)(bh * NDK + d) * NS + s0 + si;
    *reinterpret_cast<float4*>(dp)     = oa;
    *reinterpret_cast<float4*>(dp + 4) = ob;
}

// ---------------------------------------------------------------------------
// Fused attention (pure VALU). grid = B*H*64 (one block per (b,h,16-row tile)),
// block 256 = 4 waves; wave rg owns rows rg*4..rg*4+3; lane kl owns key pair
// (2*kl, 2*kl+1) within each 128-key chunk. LDS ~49.3 KB -> 3 blocks/CU.
// ---------------------------------------------------------------------------
__global__ __launch_bounds__(256) void attn_kernel(
    const float* __restrict__ q_ws, const float* __restrict__ kT,
    const float* __restrict__ vT, const int* __restrict__ mask,
    float* __restrict__ out0, float* __restrict__ out_attn)
{
    __shared__ float kc[16][128];     // chunk of kT  [d][j_local]
    __shared__ float vc[16][128];     // chunk of vT
    __shared__ short strip[16][1032]; // E (unnormalized, masked) bf16, padded
    __shared__ float rzrow[16];

    const int tid = threadIdx.x;
    const int rg = tid >> 6;          // wave id = row group
    const int kl = tid & 63;
    const int bh = blockIdx.x >> 6, mt = blockIdx.x & 63;
    const int b = bh >> 4, h = bh & 15;
    const int mbase = mt * 16;

    // q rows for this wave (wave-uniform broadcast loads)
    float qreg[4][16];
#pragma unroll
    for (int r = 0; r < 4; ++r) {
        const float* qp = q_ws + (size_t)(b * NS + mbase + rg * 4 + r) * ND + h * NDK;
#pragma unroll
        for (int d4 = 0; d4 < 4; ++d4) {
            const float4 qv = *reinterpret_cast<const float4*>(qp + d4 * 4);
            qreg[r][d4 * 4 + 0] = qv.x; qreg[r][d4 * 4 + 1] = qv.y;
            qreg[r][d4 * 4 + 2] = qv.z; qreg[r][d4 * 4 + 3] = qv.w;
        }
    }

    float zacc[4] = {0.f, 0.f, 0.f, 0.f};
    float ctx[4][16];
#pragma unroll
    for (int r = 0; r < 4; ++r)
#pragma unroll
        for (int d = 0; d < 16; ++d) ctx[r][d] = 0.f;

    for (int c = 0; c < 8; ++c) {
        const int cb = c * 128;
        __syncthreads();  // previous chunk fully consumed before restaging
        for (int f = tid; f < 512; f += 256) {
            const int d = f >> 5, s4 = (f & 31) * 4;
            *reinterpret_cast<float4*>(&kc[d][s4]) = *reinterpret_cast<const float4*>(
                kT + (size_t)(bh * NDK + d) * NS + cb + s4);
            *reinterpret_cast<float4*>(&vc[d][s4]) = *reinterpret_cast<const float4*>(
                vT + (size_t)(bh * NDK + d) * NS + cb + s4);
        }
        __syncthreads();

        const int j0 = cb + 2 * kl;
        const int2 mk = *reinterpret_cast<const int2*>(mask + b * NS + j0);

        float sa[4] = {0.f, 0.f, 0.f, 0.f}, sb[4] = {0.f, 0.f, 0.f, 0.f};
#pragma unroll
        for (int d = 0; d < 16; ++d) {
            const float2 kv = *reinterpret_cast<const float2*>(&kc[d][2 * kl]);
#pragma unroll
            for (int r = 0; r < 4; ++r) {
                sa[r] += qreg[r][d] * kv.x;
                sb[r] += qreg[r][d] * kv.y;
            }
        }

        float ea[4], eb[4];
#pragma unroll
        for (int r = 0; r < 4; ++r) {
            // clamp scrubs NaN/inf (fmaxf(NaN,c)=c) and bounds exp; masked -> exact 0
            const float xa = fminf(fmaxf(sa[r] * 0.25f, -87.f), 80.f);
            const float xb = fminf(fmaxf(sb[r] * 0.25f, -87.f), 80.f);
            ea[r] = mk.x ? __expf(xa) : 0.f;
            eb[r] = mk.y ? __expf(xb) : 0.f;
            zacc[r] += ea[r] + eb[r];
            const unsigned int pk =
                (unsigned int)f2bf(ea[r]) | ((unsigned int)f2bf(eb[r]) << 16);
            *reinterpret_cast<unsigned int*>(&strip[rg * 4 + r][j0]) = pk;
        }

#pragma unroll
        for (int d = 0; d < 16; ++d) {
            const float2 vv = *reinterpret_cast<const float2*>(&vc[d][2 * kl]);
#pragma unroll
            for (int r = 0; r < 4; ++r)
                ctx[r][d] += ea[r] * vv.x + eb[r] * vv.y;
        }
    }

    // per-row z across the wave (each row belongs to exactly one wave)
#pragma unroll
    for (int m = 1; m < 64; m <<= 1)
#pragma unroll
        for (int r = 0; r < 4; ++r)
            zacc[r] += __shfl_xor(zacc[r], m, 64);
    float rz[4];
#pragma unroll
    for (int r = 0; r < 4; ++r) rz[r] = 1.f / (zacc[r] + 1e-8f);
    if (kl == 0) {
#pragma unroll
        for (int r = 0; r < 4; ++r) rzrow[rg * 4 + r] = rz[r];
    }
    __syncthreads();

    // normalized attn_w write: thread t owns cols 4t..4t+3 of every row (float4)
    {
        const size_t abase = ((size_t)bh * NS + mbase) * NS;
        const int c4 = tid * 4;
#pragma unroll 4
        for (int r = 0; r < 16; ++r) {
            const float rzr = rzrow[r];
            const uint2 raw = *reinterpret_cast<const uint2*>(&strip[r][c4]);
            float4 o = {bf2f(raw.x & 0xffffu) * rzr, bf2f(raw.x >> 16) * rzr,
                        bf2f(raw.y & 0xffffu) * rzr, bf2f(raw.y >> 16) * rzr};
            *reinterpret_cast<float4*>(out_attn + abase + (size_t)r * NS + c4) = o;
        }
    }

    // context reduce across the wave; every lane ends with all 4x16 sums
#pragma unroll
    for (int m = 1; m < 64; m <<= 1)
#pragma unroll
        for (int r = 0; r < 4; ++r)
#pragma unroll
            for (int d = 0; d < 16; ++d)
                ctx[r][d] += __shfl_xor(ctx[r][d], m, 64);

    const int rr = kl >> 4, dd = kl & 15;
    out0[(size_t)(b * NS + mbase + rg * 4 + rr) * ND + h * NDK + dd] =
        ctx[rr][dd] * rz[rr];
}

extern "C" void kernel_launch(void* const* d_in, const int* in_sizes, int n_in,
                              void* d_out, int out_size, void* d_ws, size_t ws_size,
                              hipStream_t stream) {
    const float* Q  = (const float*)d_in[0];
    const float* K  = (const float*)d_in[1];
    const float* V  = (const float*)d_in[2];
    const int*   mk = (const int*)d_in[3];
    const float* Wq = (const float*)d_in[4];
    const float* bq = (const float*)d_in[5];
    const float* Wk = (const float*)d_in[6];
    const float* Wv = (const float*)d_in[7];
    const float* bv = (const float*)d_in[8];

    float* out0     = (float*)d_out;                 // [16,1024,256]
    float* out_attn = out0 + (size_t)NB * NS * ND;   // [16,16,1024,1024]

    const size_t nElem = (size_t)NB * NS * ND;       // 4,194,304
    const size_t ws_needed = 5 * nElem * sizeof(float);  // ~84 MB (fit in round 2)
    if (ws_size < ws_needed) {
        return;  // diagnostic signature: absmax == max|ref|
    }
    float* q_ws = (float*)d_ws;           // [B,S,256]
    float* k_ws = q_ws + nElem;           // [B,S,256]
    float* v_ws = k_ws + nElem;           // [B,S,256]
    float* kT   = v_ws + nElem;           // [B*H, DK, S]
    float* vT   = kT + nElem;             // [B*H, DK, S]

    dim3 pgrid(NB * NS / 32, 3);
    proj_kernel<<<pgrid, 256, 0, stream>>>(Q, K, V, Wq, bq, Wk, Wv, bv,
                                           q_ws, k_ws, v_ws);

    dim3 tgrid(NB * NH * 8, 2);
    transpose_kernel<<<tgrid, 256, 0, stream>>>(k_ws, v_ws, kT, vT);

    dim3 agrid(NB * NH * (NS / 16));
    attn_kernel<<<agrid, 256, 0, stream>>>(q_ws, kT, vT, mk, out0, out_attn);
}